// Round 1
// 346.400 us; speedup vs baseline: 1.0394x; 1.0394x over previous
//
#include <hip/hip_runtime.h>
#include <math.h>

#define BN_EPS 1e-5f

typedef float f4 __attribute__((ext_vector_type(4)));

// ---------------------------------------------------------------------------
// Compile-time 7->64 bilinear resize column-sum weights (half-pixel centers,
// clamped edge indices == jax's renormalized-edge bilinear, verified by the
// previous session's passing pos_mean_kernel which used the identical
// arithmetic at runtime). All intermediate values are exact in binary
// (src = (14i-57)/128), so constexpr double == runtime float bit-for-bit.
// c49[p*7+q] = W[p]*W[q] so mean(pos_up[c]) = (1/4096) * sum_k c49[k]*pos[c,k].
// ---------------------------------------------------------------------------
struct C49 { float c[49]; };

constexpr C49 make_c49() {
    float w[7] = {0.f, 0.f, 0.f, 0.f, 0.f, 0.f, 0.f};
    for (int i = 0; i < 64; ++i) {
        double src = (i + 0.5) * (7.0 / 64.0) - 0.5;
        int   fl  = (src < 0.0) ? -1 : (int)src;   // floor for src in (-0.45, 6.45)
        double f  = src - fl;
        int i1 = fl + 1;
        int p0 = fl < 0 ? 0 : (fl > 6 ? 6 : fl);
        int p1 = i1 < 0 ? 0 : (i1 > 6 ? 6 : i1);
        w[p0] += (float)(1.0 - f);
        w[p1] += (float)f;
    }
    C49 r{};
    for (int p = 0; p < 7; ++p)
        for (int q = 0; q < 7; ++q)
            r.c[p * 7 + q] = w[p] * w[q];          // float mul, matches old runtime
    return r;
}

// ---------------------------------------------------------------------------
// Kernel A (fused): pooled[b*512+c] = mean(x[b,c,:,:]) + mean(pos_up[c,:,:]).
// One wave per (b,c) row (16 KiB contiguous). 64 lanes x 16 float4 NT loads
// (x is pure streaming, zero reuse -> bypass L2 with nt), and lanes 0..48
// additionally fold in pos[c,k]*c49[k] (196 B coalesced, L2-hot after first
// touch, hidden under the HBM stream). One shfl-xor reduction covers both.
// This kernel IS the HBM roofline cost (268 MB read).
// ---------------------------------------------------------------------------
__global__ __launch_bounds__(256) void pool_pos_kernel(
    const float* __restrict__ x, const float* __restrict__ pos,
    float* __restrict__ pooled)
{
    constexpr C49 COEF = make_c49();

    const int row  = (int)((blockIdx.x * blockDim.x + threadIdx.x) >> 6); // 0..16383
    const int lane = threadIdx.x & 63;
    const int c    = row & 511;

    float sum = 0.f;
    if (lane < 49)
        sum = pos[c * 49 + lane] * COEF.c[lane];

    const f4* xr = reinterpret_cast<const f4*>(x) + (size_t)row * 1024;
#pragma unroll
    for (int j = 0; j < 16; ++j) {
        f4 v = __builtin_nontemporal_load(xr + j * 64 + lane);
        sum += (v.x + v.y) + (v.z + v.w);
    }
#pragma unroll
    for (int off = 32; off > 0; off >>= 1)
        sum += __shfl_xor(sum, off, 64);

    if (lane == 0)
        pooled[row] = sum * (1.0f / 4096.0f);
}

// ---------------------------------------------------------------------------
// Kernel B: y[b,o] = relu(BN(dot(pooled[b,:], conv_w[o,:]) + conv_b[o])).
// One wave per (b, o-pair): the pooled fragment is loaded once per lane and
// reused for two conv_w rows -> half the waves of one-output-per-wave.
// conv_w (1 MiB, 32x reuse across b) stays on the cached path (no NT).
// ---------------------------------------------------------------------------
__global__ __launch_bounds__(256) void matmul_bn_kernel(
    const float* __restrict__ pooled, const float* __restrict__ conv_w,
    const float* __restrict__ conv_b,
    const float* __restrict__ bn_gamma, const float* __restrict__ bn_beta,
    const float* __restrict__ bn_mean,  const float* __restrict__ bn_var,
    float* __restrict__ out)
{
    const int wid  = (int)((blockIdx.x * blockDim.x + threadIdx.x) >> 6); // 0..8191
    const int lane = threadIdx.x & 63;
    const int b    = wid >> 8;          // 0..31
    const int o0   = (wid & 255) * 2;   // even output index
    const int o1   = o0 + 1;

    const f4* pr = reinterpret_cast<const f4*>(pooled) + b * 128;
    const f4* w0 = reinterpret_cast<const f4*>(conv_w) + o0 * 128;
    const f4* w1 = reinterpret_cast<const f4*>(conv_w) + o1 * 128;

    float s0 = 0.f, s1 = 0.f;
#pragma unroll
    for (int j = 0; j < 2; ++j) {
        f4 p4 = pr[j * 64 + lane];
        f4 a4 = w0[j * 64 + lane];
        f4 b4 = w1[j * 64 + lane];
        s0 += p4.x * a4.x + p4.y * a4.y + p4.z * a4.z + p4.w * a4.w;
        s1 += p4.x * b4.x + p4.y * b4.y + p4.z * b4.z + p4.w * b4.w;
    }
#pragma unroll
    for (int off = 32; off > 0; off >>= 1) {
        s0 += __shfl_xor(s0, off, 64);
        s1 += __shfl_xor(s1, off, 64);
    }

    if (lane == 0) {
        float y0 = s0 + conv_b[o0];
        y0 = bn_gamma[o0] * (y0 - bn_mean[o0]) * rsqrtf(bn_var[o0] + BN_EPS) + bn_beta[o0];
        float y1 = s1 + conv_b[o1];
        y1 = bn_gamma[o1] * (y1 - bn_mean[o1]) * rsqrtf(bn_var[o1] + BN_EPS) + bn_beta[o1];
        const int base = b * 512 + o0;
        out[base]     = y0 > 0.f ? y0 : 0.f;
        out[base + 1] = y1 > 0.f ? y1 : 0.f;
    }
}

extern "C" void kernel_launch(void* const* d_in, const int* in_sizes, int n_in,
                              void* d_out, int out_size, void* d_ws, size_t ws_size,
                              hipStream_t stream) {
    const float* x        = (const float*)d_in[0];   // (32,512,64,64)
    const float* pos      = (const float*)d_in[1];   // (1,512,7,7)
    const float* conv_w   = (const float*)d_in[2];   // (512,512)
    const float* conv_b   = (const float*)d_in[3];   // (512,)
    const float* bn_gamma = (const float*)d_in[4];
    const float* bn_beta  = (const float*)d_in[5];
    const float* bn_mean  = (const float*)d_in[6];
    const float* bn_var   = (const float*)d_in[7];
    float* out = (float*)d_out;                      // (32,512,1,1) fp32

    float* pooled = (float*)d_ws;                    // 16384 floats

    pool_pos_kernel<<<4096, 256, 0, stream>>>(x, pos, pooled);
    matmul_bn_kernel<<<2048, 256, 0, stream>>>(pooled, conv_w, conv_b,
                                               bn_gamma, bn_beta, bn_mean, bn_var,
                                               out);
}